// Round 6
// baseline (129.367 us; speedup 1.0000x reference)
//
#include <hip/hip_runtime.h>
#include <hip/hip_bf16.h>
#include <stdint.h>

// out = X @ Bbig + bias; X = (32768 x 1024) fp32 (real||imag)
//   n<512:  B[k][n] = Wr[n][k] (k<512), -Wi[n][k-512] (k>=512)
//   n>=512: B[k][n] = Wi[n-512][k] (k<512), Wr[n-512][k-512] (k>=512)
// Split plan (R3 data path + m201 8-phase schedule):
//   (1) build swizzled fp16 B tile-image (2 MB)
//   (2) convert x -> swizzled fp16 A tile-image (64 MB)
//   (3) GEMM 256x256/BK=64, 8 waves (2Mx4N), 8 phases per 2 K-tiles:
//       per phase {frag ds_reads | 2 quarter-tile gload_lds | bar |
//                  lgkmcnt(0) | setprio(1) 16xMFMA setprio(0) | bar},
//       counted s_waitcnt vmcnt(6) ONLY at phases 4 and 8 (3 stages = 6
//       loads stay in flight across the K-tile boundary; no vmcnt(0)
//       in steady state).

typedef _Float16 half8 __attribute__((ext_vector_type(8)));
typedef _Float16 half4v __attribute__((ext_vector_type(4)));
typedef float f32x4 __attribute__((ext_vector_type(4)));

typedef __attribute__((address_space(3))) void* lds_ptr_t;
typedef const __attribute__((address_space(1))) void* gbl_ptr_t;

__device__ __forceinline__ void gload_lds16(const void* g, void* s) {
  // lane l's 16B from per-lane g land at (wave-uniform) s + l*16
  __builtin_amdgcn_global_load_lds((gbl_ptr_t)g, (lds_ptr_t)s, 16, 0, 0);
}

#define BARF() asm volatile("s_barrier" ::: "memory")
#define LGKM0() asm volatile("s_waitcnt lgkmcnt(0)" ::: "memory")
#define VMC6() asm volatile("s_waitcnt vmcnt(6)" ::: "memory")
#define VMC0() asm volatile("s_waitcnt vmcnt(0)" ::: "memory")
#define PRIO1() __builtin_amdgcn_s_setprio(1)
#define PRIO0() __builtin_amdgcn_s_setprio(0)

// Tile byte layout (32 KB per 256-row x 64-col fp16 tile):
//   byte = row*128 + ((kcol*2) ^ ((row&7)<<4))   -- XOR bank swizzle
// Quarter q = rows q*64..q*64+63 = bytes q*8192..+8191 (contiguous).

// ---------------- Kernel 1: swizzled B image (validated r2-r5) ----------------
__global__ void build_bt(const float* __restrict__ G1R, const float* __restrict__ G2R,
                         const float* __restrict__ G1I, const float* __restrict__ G2I,
                         _Float16* __restrict__ BTimg) {
  int idx = blockIdx.x * 256 + threadIdx.x;  // 0 .. 1M-1
  int kcol = idx & 63;
  int row  = (idx >> 6) & 255;
  int kt   = (idx >> 14) & 15;
  int nt   = idx >> 18;
  int n = nt * 256 + row;
  int k = kt * 64 + kcol;
  int o = n & 511, i = k & 511;
  bool imagOut = n >= 512, kHi = k >= 512;
  const float* G1; const float* G2; float sign = 1.0f;
  if (imagOut == kHi) { G1 = G1R; G2 = G2R; }
  else { G1 = G1I; G2 = G2I; if (!imagOut) sign = -1.0f; }
  int b = o >> 4, e = o & 15, d = i >> 4, g = i & 15;
  float w = 0.0f;
#pragma unroll
  for (int c = 0; c < 4; ++c)
    w += G1[b * 128 + c * 32 + d] * G2[c * 256 + e * 16 + g];
  size_t byteoff = ((size_t)(nt * 16 + kt) << 15) + (size_t)row * 128
                 + ((kcol * 2) ^ ((row & 7) << 4));
  *(_Float16*)((char*)BTimg + byteoff) = (_Float16)(sign * w);
}

// ---------------- Kernel 2: X fp32 -> swizzled fp16 A image (validated r3) ----
__global__ __launch_bounds__(256) void build_at(const float* __restrict__ A,
                                                _Float16* __restrict__ Aimg) {
  const int tid = threadIdx.x;
  const int kt = blockIdx.x & 15, mt = blockIdx.x >> 4;
  const float* src = A + (size_t)mt * 256 * 1024 + kt * 64;
  char* dst = (char*)Aimg + ((size_t)(mt * 16 + kt) << 15);
  const int cg = tid & 15;        // col group (4 floats)
  const int rb = tid >> 4;        // row base
#pragma unroll
  for (int r = 0; r < 16; ++r) {
    int row = rb + r * 16;        // 0..255
    float4 v = *(const float4*)(src + (size_t)row * 1024 + cg * 4);
    half4v h = { (_Float16)v.x, (_Float16)v.y, (_Float16)v.z, (_Float16)v.w };
    *(half4v*)(dst + row * 128 + ((cg * 8) ^ ((row & 7) << 4))) = h;
  }
}

// ---------------- Kernel 3: GEMM, 8-phase counted-vmcnt schedule ----------------
__global__ __launch_bounds__(512, 2) void tt_gemm(
    const _Float16* __restrict__ Aimg, const _Float16* __restrict__ Bimg,
    const float* __restrict__ bias_r, const float* __restrict__ bias_i,
    float* __restrict__ C) {
  __shared__ __align__(16) _Float16 Als[2][16384];  // 32KB/buf, swizzled
  __shared__ __align__(16) _Float16 Bls[2][16384];

  const int tid = threadIdx.x;
  const int bid = blockIdx.x;
  // XCD swizzle (512 % 8 == 0): 64 contiguous per XCD, nt fastest (A L2 reuse)
  const int bid2 = (bid & 7) * 64 + (bid >> 3);
  const int mt = bid2 >> 2, nt = bid2 & 3;

  const int lane = tid & 63, wid = tid >> 6;
  const int wm = wid >> 2, wn = wid & 3;   // wave -> 128(M) x 64(N) C subtile
  const int lr = lane & 15, lq = lane >> 4;

  f32x4 acc[8][4] = {};
  half8 afr0[4][2], afr1[4][2], bfr0[2][2], bfr1[2][2];

  const char* Abase = (const char*)Aimg + ((size_t)mt << 19);  // 16 tiles * 32KB
  const char* Bbase = (const char*)Bimg + ((size_t)nt << 19);
  const int qoff = wid * 1024 + lane * 16;   // within an 8KB quarter
  const int qdst = wid * 1024;

  auto stageQ = [&](const char* base, int t, int q, _Float16* buf) {
    gload_lds16(base + ((size_t)t << 15) + (q << 13) + qoff,
                (char*)buf + (q << 13) + qdst);
  };
  auto lda = [&](const _Float16* buf, int mh, half8 (&af)[4][2]) {
#pragma unroll
    for (int mf = 0; mf < 4; ++mf)
#pragma unroll
      for (int kk = 0; kk < 2; ++kk) {
        int row = wm * 128 + mh * 64 + mf * 16 + lr;
        int byte = row * 128 + ((kk * 64 + lq * 16) ^ ((row & 7) << 4));
        af[mf][kk] = *(const half8*)((const char*)buf + byte);
      }
  };
  auto ldb = [&](const _Float16* buf, int nh, half8 (&bf)[2][2]) {
#pragma unroll
    for (int j = 0; j < 2; ++j)
#pragma unroll
      for (int kk = 0; kk < 2; ++kk) {
        int row = wn * 64 + (nh * 2 + j) * 16 + lr;
        int byte = row * 128 + ((kk * 64 + lq * 16) ^ ((row & 7) << 4));
        bf[j][kk] = *(const half8*)((const char*)buf + byte);
      }
  };
  auto mmaq = [&](half8 (&af)[4][2], half8 (&bf)[2][2], int mb, int nb) {
#pragma unroll
    for (int mf = 0; mf < 4; ++mf)
#pragma unroll
      for (int j = 0; j < 2; ++j)
#pragma unroll
        for (int kk = 0; kk < 2; ++kk)
          acc[mb + mf][nb + j] = __builtin_amdgcn_mfma_f32_16x16x32_f16(
              af[mf][kk], bf[j][kk], acc[mb + mf][nb + j], 0, 0, 0);
  };

  _Float16* A0 = Als[0]; _Float16* A1 = Als[1];
  _Float16* B0 = Bls[0]; _Float16* B1 = Bls[1];

  // ---- prologue: T0 full (8 quarters), then T1.AQ0,AQ2,BQ0..3 (6 loads) ----
#pragma unroll
  for (int q = 0; q < 4; ++q) stageQ(Abase, 0, q, A0);
#pragma unroll
  for (int q = 0; q < 4; ++q) stageQ(Bbase, 0, q, B0);
  stageQ(Abase, 1, 0, A1); stageQ(Abase, 1, 2, A1);
  stageQ(Bbase, 1, 0, B1); stageQ(Bbase, 1, 1, B1);
  stageQ(Bbase, 1, 2, B1); stageQ(Bbase, 1, 3, B1);
  VMC6();   // oldest 8 (= all of T0) complete; T1's 6 stay in flight
  BARF();

  // ---- main loop: iter i computes T0=2i (buf0) and T1=2i+1 (buf1) ----
  for (int i = 0; i < 8; ++i) {
    const int t1 = 2 * i + 1, t2 = 2 * i + 2, t3 = 2 * i + 3;
    const bool pf = (i < 7);
    // Ph1: Q(0,0) of T0; stage T1.AQ1,AQ3 (regions freed prev Ph8)
    lda(A0, 0, afr0); ldb(B0, 0, bfr0);
    stageQ(Abase, t1, 1, A1); stageQ(Abase, t1, 3, A1);
    BARF(); LGKM0(); PRIO1(); mmaq(afr0, bfr0, 0, 0); PRIO0(); BARF();
    // Ph2: Q(0,1); stage T2.AQ0,AQ2 (freed after Ph1)
    ldb(B0, 1, bfr1);
    if (pf) { stageQ(Abase, t2, 0, A0); stageQ(Abase, t2, 2, A0); }
    BARF(); LGKM0(); PRIO1(); mmaq(afr0, bfr1, 0, 2); PRIO0(); BARF();
    // Ph3: Q(1,1); stage T2.BQ0,BQ1 (freed after Ph2)
    lda(A0, 1, afr1);
    if (pf) { stageQ(Bbase, t2, 0, B0); stageQ(Bbase, t2, 1, B0); }
    BARF(); LGKM0(); PRIO1(); mmaq(afr1, bfr1, 4, 2); PRIO0(); BARF();
    // Ph4: Q(1,0); stage T2.BQ2,BQ3; counted wait completes all of T1
    if (pf) { stageQ(Bbase, t2, 2, B0); stageQ(Bbase, t2, 3, B0); }
    BARF(); LGKM0(); PRIO1(); mmaq(afr1, bfr0, 4, 0); PRIO0();
    if (pf) { VMC6(); } else { VMC0(); }
    BARF();
    // Ph5: Q(0,0) of T1; stage T2.AQ1,AQ3 (freed after Ph3)
    lda(A1, 0, afr0); ldb(B1, 0, bfr0);
    if (pf) { stageQ(Abase, t2, 1, A0); stageQ(Abase, t2, 3, A0); }
    BARF(); LGKM0(); PRIO1(); mmaq(afr0, bfr0, 0, 0); PRIO0(); BARF();
    // Ph6: Q(0,1); stage T3.AQ0,AQ2 (freed after Ph5)
    ldb(B1, 1, bfr1);
    if (pf) { stageQ(Abase, t3, 0, A1); stageQ(Abase, t3, 2, A1); }
    BARF(); LGKM0(); PRIO1(); mmaq(afr0, bfr1, 0, 2); PRIO0(); BARF();
    // Ph7: Q(1,1); stage T3.BQ0,BQ1 (freed after Ph6)
    lda(A1, 1, afr1);
    if (pf) { stageQ(Bbase, t3, 0, B1); stageQ(Bbase, t3, 1, B1); }
    BARF(); LGKM0(); PRIO1(); mmaq(afr1, bfr1, 4, 2); PRIO0(); BARF();
    // Ph8: Q(1,0); stage T3.BQ2,BQ3; counted wait completes all of T2
    if (pf) { stageQ(Bbase, t3, 2, B1); stageQ(Bbase, t3, 3, B1); }
    BARF(); LGKM0(); PRIO1(); mmaq(afr1, bfr0, 4, 0); PRIO0();
    if (pf) { VMC6(); }
    BARF();
  }

  // ---- epilogue: C/D layout col=lr, row=lq*4+r ----
  const int row0 = mt * 256, col0 = nt * 256;
#pragma unroll
  for (int fn = 0; fn < 4; ++fn) {
    int col = col0 + wn * 64 + fn * 16 + lr;
    float bias = (col < 512) ? bias_r[col] : bias_i[col - 512];
#pragma unroll
    for (int fm = 0; fm < 8; ++fm) {
      int r0 = row0 + wm * 128 + (fm >> 2) * 64 + (fm & 3) * 16 + lq * 4;
#pragma unroll
      for (int r = 0; r < 4; ++r)
        C[(size_t)(r0 + r) * 1024 + col] = acc[fm][fn][r] + bias;
    }
  }
}

extern "C" void kernel_launch(void* const* d_in, const int* in_sizes, int n_in,
                              void* d_out, int out_size, void* d_ws, size_t ws_size,
                              hipStream_t stream) {
  const float* x   = (const float*)d_in[0];
  const float* G1R = (const float*)d_in[1];
  const float* G2R = (const float*)d_in[2];
  const float* G1I = (const float*)d_in[3];
  const float* G2I = (const float*)d_in[4];
  const float* br  = (const float*)d_in[5];
  const float* bi  = (const float*)d_in[6];
  float* out = (float*)d_out;

  _Float16* Bimg = (_Float16*)d_ws;                          // 2 MB
  _Float16* Aimg = (_Float16*)((char*)d_ws + (2u << 20));    // 64 MB

  build_bt<<<4096, 256, 0, stream>>>(G1R, G2R, G1I, G2I, Bimg);
  build_at<<<2048, 256, 0, stream>>>(x, Aimg);
  tt_gemm<<<512, 512, 0, stream>>>(Aimg, Bimg, br, bi, out);
}